// Round 1
// baseline (1757.381 us; speedup 1.0000x reference)
//
#include <hip/hip_runtime.h>
#include <cmath>
#include <cstdint>

// ---------------------------------------------------------------------------
// DependencyTreeLSTM — persistent mega-kernel for the 12-level loop.
// Previous best (629 us) ran 38 dispatches/iter; the level loop's real work
// is ~25-35 us/level but measured ~46 us/level -> per-dispatch overhead
// (launch + ramp/drain + kernel-boundary cache flushes) dominates.
// This version: pack+stage+wxf prologue (3 dispatches) + ONE persistent
// kernel running all 12 levels of {fp, reduce, zcell} with a hierarchical
// device-scope grid barrier (34 barriers total).  Phase math is ported 1:1
// from the proven split kernels; zcell's split-K LDS reduce is shrunk
// 48->36 KB (own m-frag kept in regs) so 4 blocks/CU are co-resident.
// ---------------------------------------------------------------------------

#define NN    4096
#define HH    300
#define KK    8
#define LVLS  12
#define KP    320
#define NGRP  32
#define MEGA_MAX_BLK 1024

typedef __bf16  bf16x8 __attribute__((ext_vector_type(8)));
typedef float   f32x4  __attribute__((ext_vector_type(4)));

#define GAS __attribute__((address_space(1)))
#define LAS __attribute__((address_space(3)))

__device__ __forceinline__ float sigmoidf_(float x) {
    return 1.0f / (1.0f + expf(-x));
}
__device__ __forceinline__ ushort f2bf(float f) {   // f32 -> bf16, RNE
    union { float f; uint32_t u; } v; v.f = f;
    return (ushort)((v.u + 0x7fffu + ((v.u >> 16) & 1u)) >> 16);
}
__device__ __forceinline__ float bf2f(ushort u) {
    union { uint32_t u; float f; } v; v.u = ((uint32_t)u) << 16;
    return v.f;
}

// ---------------------------------------------------------------------------
// Weight packing (bf16, padded) + grid-barrier state zeroing.
//   WfP [320][320] = w_f;  Uf [320][320] = u_f;
//   Wz  [3][320][640]  g=[i|o|u], k<320 -> w_g, k>=320 -> u_g;
//   BZ[3][320] = b_wg + b_ug;  Bwf[320] = b_wf;  BUF[320] = b_uf.
//   BAR[2048]  = grid-barrier counters/epoch (zeroed every replay).
// ---------------------------------------------------------------------------
__global__ __launch_bounds__(256)
void pack_weights(
    const float* __restrict__ wi, const float* __restrict__ bwi,
    const float* __restrict__ ui, const float* __restrict__ bui,
    const float* __restrict__ wf, const float* __restrict__ bwf,
    const float* __restrict__ uf, const float* __restrict__ buf_,
    const float* __restrict__ wo, const float* __restrict__ bwo,
    const float* __restrict__ uo, const float* __restrict__ buo,
    const float* __restrict__ wu, const float* __restrict__ bwu,
    const float* __restrict__ uu, const float* __restrict__ buu,
    ushort* __restrict__ WfP, ushort* __restrict__ Uf, ushort* __restrict__ Wz,
    float* __restrict__ BZ, float* __restrict__ Bwf, float* __restrict__ BUF,
    uint32_t* __restrict__ BAR)
{
    int t = blockIdx.x * 256 + threadIdx.x;
    if (t < 102400) {                                    // WfP
        int r = t / KP, k = t % KP;
        WfP[t] = f2bf((r < 300 && k < 300) ? wf[r * 300 + k] : 0.f);
    } else if (t < 204800) {                             // Uf
        int x = t - 102400, r = x / KP, k = x % KP;
        Uf[x] = f2bf((r < 300 && k < 300) ? uf[r * 300 + k] : 0.f);
    } else if (t < 819200) {                             // Wz [3][320][640]
        int x = t - 204800;
        int g = x / 204800, rem = x % 204800;
        int r = rem / 640, k = rem % 640;
        const float* W = (g == 0) ? wi : (g == 1) ? wo : wu;
        const float* U = (g == 0) ? ui : (g == 1) ? uo : uu;
        float v = 0.f;
        if (r < 300) {
            if (k < 320) { if (k < 300) v = W[r * 300 + k]; }
            else         { int kk = k - 320; if (kk < 300) v = U[r * 300 + kk]; }
        }
        Wz[x] = f2bf(v);
    } else if (t < 820160) {                             // BZ [3][320]
        int x = t - 819200, g = x / KP, r = x % KP;
        const float* bw = (g == 0) ? bwi : (g == 1) ? bwo : bwu;
        const float* bu = (g == 0) ? bui : (g == 1) ? buo : buu;
        BZ[x] = (r < 300) ? bw[r] + bu[r] : 0.f;
    } else if (t < 820480) {                             // Bwf
        int r = t - 820160;
        Bwf[r] = (r < 300) ? bwf[r] : 0.f;
    } else if (t < 820800) {                             // BUF
        int r = t - 820480;
        BUF[r] = (r < 300) ? buf_[r] : 0.f;
    } else if (t < 822848) {                             // barrier state
        BAR[t - 820800] = 0u;
    }
}

// ---------------------------------------------------------------------------
// Stage all 12 levels of X (bf16, K-padded).
// ---------------------------------------------------------------------------
__global__ __launch_bounds__(256)
void stage_all(const int* __restrict__ word_ids, const float* __restrict__ emb,
               ushort* __restrict__ X)
{
    int idx = blockIdx.x * 256 + threadIdx.x;      // 12*4096*80
    int nl = idx / 80, kc = idx % 80, k = kc * 4;
    ushort4 o;
    if (kc < 75) {
        const float2* p = reinterpret_cast<const float2*>(
            emb + (size_t)word_ids[nl] * 300 + k);
        float2 v0 = p[0], v1 = p[1];
        o.x = f2bf(v0.x); o.y = f2bf(v0.y); o.z = f2bf(v1.x); o.w = f2bf(v1.y);
    } else {
        o.x = o.y = o.z = o.w = 0;
    }
    *reinterpret_cast<ushort4*>(X + (size_t)nl * KP + k) = o;
}

// ---------------------------------------------------------------------------
// 128x64 G=1 GEMM core (4 waves 2x2, wave 64x32) - for the big WXF_all GEMM.
// ---------------------------------------------------------------------------
template <int NSTEP>
__device__ __forceinline__
void gemm128_core(const ushort* __restrict__ A, const ushort* __restrict__ B,
                  int m0, int n0,
                  ushort (&As)[4][128][8], ushort (&Bs)[4][64][8],
                  f32x4 (&acc)[4][2])
{
    const int t  = threadIdx.x;
    const int l  = t & 63, w = t >> 6;
    const int m_off = (w >> 1) * 64, n_off = (w & 1) * 32;
    const int kq = l >> 4, lr = l & 15;
    const int arow = t & 127, akb0 = t >> 7;
    const int brow = t & 63,  bkb  = t >> 6;

    for (int s = 0; s < NSTEP; ++s) {
        #pragma unroll
        for (int c = 0; c < 2; ++c) {
            const int akb = akb0 + c * 2;
            const int kc  = s * 4 + akb;
            const ushort* ga = A + (size_t)(m0 + arow) * KP + (size_t)kc * 8;
            __builtin_amdgcn_global_load_lds((const GAS void*)ga,
                (LAS void*)&As[akb][arow][0], 16, 0, 0);
        }
        {
            const int kc = s * 4 + bkb;
            const ushort* gb = B + (size_t)(n0 + brow) * KP + (size_t)kc * 8;
            __builtin_amdgcn_global_load_lds((const GAS void*)gb,
                (LAS void*)&Bs[bkb][brow][0], 16, 0, 0);
        }
        __syncthreads();

        bf16x8 af[4], bfr[2];
        #pragma unroll
        for (int mi = 0; mi < 4; ++mi)
            af[mi] = *reinterpret_cast<const bf16x8*>(
                &As[kq][m_off + mi * 16 + lr][0]);
        #pragma unroll
        for (int ni = 0; ni < 2; ++ni)
            bfr[ni] = *reinterpret_cast<const bf16x8*>(
                &Bs[kq][n_off + ni * 16 + lr][0]);
        #pragma unroll
        for (int mi = 0; mi < 4; ++mi)
            #pragma unroll
            for (int ni = 0; ni < 2; ++ni)
                acc[mi][ni] = __builtin_amdgcn_mfma_f32_16x16x32_bf16(
                    af[mi], bfr[ni], acc[mi][ni], 0, 0, 0);
        __syncthreads();
    }
}

// WXF_all = X_all[49152][320] @ w_f^T + b_wf -> bf16 [49152][320].  Grid 1920.
__global__ __launch_bounds__(256)
void wxf_all_kernel(const ushort* __restrict__ Xall, const ushort* __restrict__ WfP,
                    const float* __restrict__ Bwf, ushort* __restrict__ WXFall)
{
    __shared__ __attribute__((aligned(16))) ushort As[4][128][8];
    __shared__ __attribute__((aligned(16))) ushort Bs[4][64][8];

    const int b  = blockIdx.x;
    const int bj = (b % 8) * 240 + b / 8;         // bijective (1920 % 8 == 0)
    const int m0 = (bj / 5) * 128, n0 = (bj % 5) * 64;

    f32x4 acc[4][2] = {};
    gemm128_core<10>(Xall, WfP, m0, n0, As, Bs, acc);

    const int t = threadIdx.x, l = t & 63, w = t >> 6;
    const int m_off = (w >> 1) * 64, n_off = (w & 1) * 32;
    const int col = l & 15, r0 = (l >> 4) * 4;
    #pragma unroll
    for (int mi = 0; mi < 4; ++mi) {
        #pragma unroll
        for (int ni = 0; ni < 2; ++ni) {
            const int gn = n0 + n_off + ni * 16 + col;
            const float bb = Bwf[gn];
            #pragma unroll
            for (int r = 0; r < 4; ++r) {
                const int gm = m0 + m_off + mi * 16 + r0 + r;
                WXFall[(size_t)gm * KP + gn] = f2bf(acc[mi][ni][r] + bb);
            }
        }
    }
}

// ---------------------------------------------------------------------------
// Hierarchical device-scope grid barrier.  NGRP group counters (128 B apart)
// + root counter + monotonic epoch.  Last arriver resets counters BEFORE the
// epoch release, so state is reusable immediately.  Spin is RELAXED (no
// per-iteration cache invalidate); one acquire fence on exit.
// bar layout (uint32): [0..NGRP*32)   group counters (stride 32 words)
//                      [NGRP*32]      root counter
//                      [NGRP*32+32]   epoch
// ---------------------------------------------------------------------------
__device__ __forceinline__ void gbar(uint32_t* bar, int nblk, uint32_t& ep)
{
    __syncthreads();
    if (threadIdx.x == 0) {
        ++ep;
        const int g  = blockIdx.x & (NGRP - 1);
        const uint32_t gs = (uint32_t)(nblk >> 5);       // blocks per group
        uint32_t* gc  = bar + (size_t)g * 32;
        uint32_t* rc  = bar + (size_t)NGRP * 32;
        uint32_t* epo = bar + (size_t)NGRP * 32 + 32;
        __builtin_amdgcn_fence(__ATOMIC_RELEASE, "agent");
        uint32_t prev = __hip_atomic_fetch_add(gc, 1u, __ATOMIC_ACQ_REL,
                                               __HIP_MEMORY_SCOPE_AGENT);
        if (prev == gs - 1u) {
            __hip_atomic_store(gc, 0u, __ATOMIC_RELAXED, __HIP_MEMORY_SCOPE_AGENT);
            uint32_t p2 = __hip_atomic_fetch_add(rc, 1u, __ATOMIC_ACQ_REL,
                                                 __HIP_MEMORY_SCOPE_AGENT);
            if (p2 == (uint32_t)(NGRP - 1)) {
                __hip_atomic_store(rc, 0u, __ATOMIC_RELAXED,
                                   __HIP_MEMORY_SCOPE_AGENT);
                __hip_atomic_store(epo, ep, __ATOMIC_RELEASE,
                                   __HIP_MEMORY_SCOPE_AGENT);
            }
        }
        while (__hip_atomic_load(epo, __ATOMIC_RELAXED,
                                 __HIP_MEMORY_SCOPE_AGENT) < ep) {
            __builtin_amdgcn_s_sleep(2);
        }
        __builtin_amdgcn_fence(__ATOMIC_ACQUIRE, "agent");
    }
    __syncthreads();
}

// ---------------------------------------------------------------------------
// Persistent mega-kernel: all 12 levels of {fp, reduce, zcell}.
// grid = nblk (co-resident; <= 1024), 256 threads, 36 KB LDS, VGPR<=128.
// ---------------------------------------------------------------------------
__global__ __launch_bounds__(256, 4)
void mega(const ushort* __restrict__ Xall, const ushort* __restrict__ WXFall,
          const ushort* __restrict__ Wz,  const float* __restrict__ BZ,
          const ushort* __restrict__ Uf,  const float* __restrict__ BUFb,
          const int* __restrict__ child_idx, const float* __restrict__ child_mask,
          ushort* __restrict__ FPbf, ushort* __restrict__ HTbf,
          float* __restrict__ SCb,  ushort* __restrict__ Hbf,
          float* __restrict__ C0,
          float* __restrict__ h_final, float* __restrict__ c_final,
          uint32_t* bar, int nblk)
{
    // split-K reduce buffer: wave w publishes its 9 non-own m-frags (36 KB)
    __shared__ __attribute__((aligned(16))) f32x4 red[4][9][64];

    const int bid = blockIdx.x;
    const int t = threadIdx.x, w = t >> 6, l = t & 63;
    const int kq = l >> 4, lr = l & 15;
    const int col = l & 15, r0 = (l >> 4) * 4;
    uint32_t ep = 0;

    for (int lev = 0; lev < LVLS; ++lev) {
        const ushort* Xlev   = Xall   + (size_t)lev * NN * KP;
        const ushort* WXFlev = WXFall + (size_t)lev * NN * KP;
        const int*    cidx   = child_idx  + (size_t)lev * NN * KK;
        const float*  cmask  = child_mask + (size_t)lev * NN * KK;

        // ----- fp phase: FP = Hbf @ Uf^T + b_uf  (640 tiles of 64x32) -----
        if (lev > 0) {
            for (int vt = bid; vt < 640; vt += nblk) {
                const int bj = (vt % 8) * 80 + vt / 8;
                const int m0 = (bj / 10) * 64, n0 = (bj % 10) * 32;
                const int m_off = (w >> 1) * 32, n_off = (w & 1) * 16;
                f32x4 acc[2] = {};
                #pragma unroll
                for (int s = 0; s < 10; ++s) {
                    const int kc = s * 4 + kq;
                    bf16x8 af[2], bf;
                    #pragma unroll
                    for (int mi = 0; mi < 2; ++mi)
                        af[mi] = *reinterpret_cast<const bf16x8*>(
                            Hbf + (size_t)(m0 + m_off + mi * 16 + lr) * KP
                                + (size_t)kc * 8);
                    bf = *reinterpret_cast<const bf16x8*>(
                            Uf + (size_t)(n0 + n_off + lr) * KP + (size_t)kc * 8);
                    #pragma unroll
                    for (int mi = 0; mi < 2; ++mi)
                        acc[mi] = __builtin_amdgcn_mfma_f32_16x16x32_bf16(
                            af[mi], bf, acc[mi], 0, 0, 0);
                }
                const int gn = n0 + n_off + col;
                const float bb = BUFb[gn];
                #pragma unroll
                for (int mi = 0; mi < 2; ++mi)
                    #pragma unroll
                    for (int r = 0; r < 4; ++r)
                        FPbf[(size_t)(m0 + m_off + mi * 16 + r0 + r) * KP + gn] =
                            f2bf(acc[mi][r] + bb);
            }
            gbar(bar, nblk, ep);
        }

        // ----- reduce phase: child gather + masked sums (1 node / wave) ---
        for (int u = bid; u < NN / 4; u += nblk) {
            const int n = u * 4 + w;
            const int base = n * KK;
            float mk[KK]; int ci[KK];
            #pragma unroll
            for (int k = 0; k < KK; ++k) {
                mk[k] = cmask[base + k];
                ci[k] = cidx[base + k];
            }
            const int h0 = l * 4;
            const bool two = (l < 11);        // chunks 64..74
            const int h1 = h0 + 256;

            const ushort4 wxu0 = *reinterpret_cast<const ushort4*>(
                &WXFlev[(size_t)n * KP + h0]);
            float wxa[4] = { bf2f(wxu0.x), bf2f(wxu0.y),
                             bf2f(wxu0.z), bf2f(wxu0.w) };
            float wxb[4] = {0.f, 0.f, 0.f, 0.f};
            if (two) {
                const ushort4 wxu1 = *reinterpret_cast<const ushort4*>(
                    &WXFlev[(size_t)n * KP + h1]);
                wxb[0] = bf2f(wxu1.x); wxb[1] = bf2f(wxu1.y);
                wxb[2] = bf2f(wxu1.z); wxb[3] = bf2f(wxu1.w);
            }
            float ht_a[4] = {0.f,0.f,0.f,0.f}, sc_a[4] = {0.f,0.f,0.f,0.f};
            float ht_b[4] = {0.f,0.f,0.f,0.f}, sc_b[4] = {0.f,0.f,0.f,0.f};

            #pragma unroll
            for (int k = 0; k < KK; ++k) {
                const float m = mk[k];
                if (m != 0.f) {
                    const size_t cr = (size_t)ci[k];
                    {
                        const ushort4 hu = *reinterpret_cast<const ushort4*>(
                            &Hbf[cr * KP + h0]);
                        const ushort4 fu = *reinterpret_cast<const ushort4*>(
                            &FPbf[cr * KP + h0]);
                        const float4 ck = *reinterpret_cast<const float4*>(
                            &C0[cr * HH + h0]);
                        ht_a[0] += m * bf2f(hu.x); ht_a[1] += m * bf2f(hu.y);
                        ht_a[2] += m * bf2f(hu.z); ht_a[3] += m * bf2f(hu.w);
                        sc_a[0] += m * sigmoidf_(wxa[0] + bf2f(fu.x)) * ck.x;
                        sc_a[1] += m * sigmoidf_(wxa[1] + bf2f(fu.y)) * ck.y;
                        sc_a[2] += m * sigmoidf_(wxa[2] + bf2f(fu.z)) * ck.z;
                        sc_a[3] += m * sigmoidf_(wxa[3] + bf2f(fu.w)) * ck.w;
                    }
                    if (two) {
                        const ushort4 hu = *reinterpret_cast<const ushort4*>(
                            &Hbf[cr * KP + h1]);
                        const ushort4 fu = *reinterpret_cast<const ushort4*>(
                            &FPbf[cr * KP + h1]);
                        const float4 ck = *reinterpret_cast<const float4*>(
                            &C0[cr * HH + h1]);
                        ht_b[0] += m * bf2f(hu.x); ht_b[1] += m * bf2f(hu.y);
                        ht_b[2] += m * bf2f(hu.z); ht_b[3] += m * bf2f(hu.w);
                        sc_b[0] += m * sigmoidf_(wxb[0] + bf2f(fu.x)) * ck.x;
                        sc_b[1] += m * sigmoidf_(wxb[1] + bf2f(fu.y)) * ck.y;
                        sc_b[2] += m * sigmoidf_(wxb[2] + bf2f(fu.z)) * ck.z;
                        sc_b[3] += m * sigmoidf_(wxb[3] + bf2f(fu.w)) * ck.w;
                    }
                }
            }
            {
                ushort4 ho;
                ho.x = f2bf(ht_a[0]); ho.y = f2bf(ht_a[1]);
                ho.z = f2bf(ht_a[2]); ho.w = f2bf(ht_a[3]);
                *reinterpret_cast<ushort4*>(&HTbf[(size_t)n * KP + h0]) = ho;
                float4 so; so.x = sc_a[0]; so.y = sc_a[1];
                so.z = sc_a[2]; so.w = sc_a[3];
                *reinterpret_cast<float4*>(&SCb[(size_t)n * KP + h0]) = so;
            }
            if (two) {
                ushort4 ho;
                ho.x = f2bf(ht_b[0]); ho.y = f2bf(ht_b[1]);
                ho.z = f2bf(ht_b[2]); ho.w = f2bf(ht_b[3]);
                *reinterpret_cast<ushort4*>(&HTbf[(size_t)n * KP + h1]) = ho;
                float4 so; so.x = sc_b[0]; so.y = sc_b[1];
                so.z = sc_b[2]; so.w = sc_b[3];
                *reinterpret_cast<float4*>(&SCb[(size_t)n * KP + h1]) = so;
            }
        }
        gbar(bar, nblk, ep);

        // ----- zcell phase: gates GEMM (split-K) + cell epilogue ----------
        const bool lastlev = (lev == LVLS - 1);
        float* cdst = lastlev ? c_final : C0;
        float* hdst = lastlev ? h_final : nullptr;
        for (int vt = bid; vt < 1216; vt += nblk) {
            const int bj = (vt & 7) * 152 + (vt >> 3);    // bijective on 1216
            const int m0 = (bj / 19) * 64, n0 = (bj % 19) * 16;

            const ushort* Abase = (w < 2) ? Xlev : HTbf;
            const int akb0 = (w < 2) ? (w * 20) : (w * 20 - 40);
            const int gkb0 = w * 20;

            f32x4 acc[3][4] = {};
            #pragma unroll
            for (int s = 0; s < 5; ++s) {
                const int kA = akb0 + s * 4 + kq;
                const int kB = gkb0 + s * 4 + kq;
                bf16x8 af[4], bfr[3];
                #pragma unroll
                for (int mi = 0; mi < 4; ++mi)
                    af[mi] = *reinterpret_cast<const bf16x8*>(
                        Abase + (size_t)(m0 + mi * 16 + lr) * KP + (size_t)kA * 8);
                #pragma unroll
                for (int g = 0; g < 3; ++g)
                    bfr[g] = *reinterpret_cast<const bf16x8*>(
                        Wz + ((size_t)g * KP + n0 + lr) * 640 + (size_t)kB * 8);
                #pragma unroll
                for (int g = 0; g < 3; ++g)
                    #pragma unroll
                    for (int mi = 0; mi < 4; ++mi)
                        acc[g][mi] = __builtin_amdgcn_mfma_f32_16x16x32_bf16(
                            af[mi], bfr[g], acc[g][mi], 0, 0, 0);
            }

            // publish the 9 non-own m-frags; keep own (mi==w) in registers
            f32x4 own[3];
            #pragma unroll
            for (int g = 0; g < 3; ++g) {
                #pragma unroll
                for (int mi = 0; mi < 4; ++mi) {
                    if (mi != w)
                        red[w][g * 3 + mi - (mi > w)][l] = acc[g][mi];
                    else
                        own[g] = acc[g][mi];
                }
            }
            __syncthreads();

            const int gn = n0 + lr;
            if (gn < 300) {
                f32x4 sg[3];
                #pragma unroll
                for (int g = 0; g < 3; ++g) {
                    f32x4 v = own[g];
                    #pragma unroll
                    for (int sw = 0; sw < 4; ++sw) {
                        if (sw != w) {
                            f32x4 u2 = red[sw][g * 3 + w - (w > sw)][l];
                            v[0] += u2[0]; v[1] += u2[1];
                            v[2] += u2[2]; v[3] += u2[3];
                        }
                    }
                    sg[g] = v;
                }
                const float bi_ = BZ[gn], bo_ = BZ[KP + gn], bu_ = BZ[2 * KP + gn];
                const int gmb = m0 + w * 16 + r0;
                #pragma unroll
                for (int r = 0; r < 4; ++r) {
                    const int gm = gmb + r;
                    const float sc = SCb[(size_t)gm * KP + gn];
                    const float ig = sigmoidf_(sg[0][r] + bi_);
                    const float og = sigmoidf_(sg[1][r] + bo_);
                    const float ug = tanhf   (sg[2][r] + bu_);
                    const float c  = ig * ug + sc;
                    const float hv = og * tanhf(c);
                    cdst[(size_t)gm * HH + gn] = c;
                    Hbf [(size_t)gm * KP + gn] = f2bf(hv);
                    if (hdst) hdst[(size_t)gm * HH + gn] = hv;
                }
            }
            __syncthreads();   // red reused next vt iteration
        }
        if (lev < LVLS - 1) gbar(bar, nblk, ep);
    }
}

// ---------------------------------------------------------------------------
extern "C" void kernel_launch(void* const* d_in, const int* in_sizes, int n_in,
                              void* d_out, int out_size, void* d_ws, size_t ws_size,
                              hipStream_t stream)
{
    const int*   word_ids   = (const int*)  d_in[0];
    const int*   child_idx  = (const int*)  d_in[1];
    const float* child_mask = (const float*)d_in[2];
    const float* emb        = (const float*)d_in[3];
    const float* w_i  = (const float*)d_in[4];  const float* b_wi = (const float*)d_in[5];
    const float* u_i  = (const float*)d_in[6];  const float* b_ui = (const float*)d_in[7];
    const float* w_f  = (const float*)d_in[8];  const float* b_wf = (const float*)d_in[9];
    const float* u_f  = (const float*)d_in[10]; const float* b_uf = (const float*)d_in[11];
    const float* w_o  = (const float*)d_in[12]; const float* b_wo = (const float*)d_in[13];
    const float* u_o  = (const float*)d_in[14]; const float* b_uo = (const float*)d_in[15];
    const float* w_u  = (const float*)d_in[16]; const float* b_wu = (const float*)d_in[17];
    const float* u_u  = (const float*)d_in[18]; const float* b_uu = (const float*)d_in[19];

    uint8_t* ws = (uint8_t*)d_ws;
    size_t off = 0;
    auto alloc = [&](size_t bytes) {
        uint8_t* p = ws + off;
        off += (bytes + 255) & ~(size_t)255;
        return p;
    };
    ushort* WfP   = (ushort*)alloc((size_t)KP * KP * 2);
    ushort* Uf    = (ushort*)alloc((size_t)KP * KP * 2);
    ushort* Wz    = (ushort*)alloc((size_t)3 * KP * 640 * 2);
    ushort* Xall  = (ushort*)alloc((size_t)LVLS * NN * KP * 2);
    ushort* WXFall= (ushort*)alloc((size_t)LVLS * NN * KP * 2);
    ushort* FPbf  = (ushort*)alloc((size_t)NN * KP * 2);
    ushort* HTbf  = (ushort*)alloc((size_t)NN * KP * 2);
    ushort* Hbf   = (ushort*)alloc((size_t)NN * KP * 2);
    float*  SCb   = (float*) alloc((size_t)NN * KP * 4);
    float*  C0    = (float*) alloc((size_t)NN * HH * 4);
    float*  BZ    = (float*) alloc(3 * KP * 4);
    float*  Bwf   = (float*) alloc(KP * 4);
    float*  BUFb  = (float*) alloc(KP * 4);
    uint32_t* BAR = (uint32_t*)alloc(2048 * 4);

    // co-resident grid size for the persistent kernel (cached; host-side
    // queries only -- safe under graph capture)
    static int g_nblk = 0;
    if (g_nblk == 0) {
        int occ = 0;
        if (hipOccupancyMaxActiveBlocksPerMultiprocessor(&occ, mega, 256, 0)
                != hipSuccess || occ < 1)
            occ = 2;                                   // conservative fallback
        int nCU = 256;
        hipDeviceProp_t prop; int dev = 0;
        if (hipGetDevice(&dev) == hipSuccess &&
            hipGetDeviceProperties(&prop, dev) == hipSuccess &&
            prop.multiProcessorCount > 0)
            nCU = prop.multiProcessorCount;
        long cap = (long)occ * (long)nCU;
        if (cap > MEGA_MAX_BLK) cap = MEGA_MAX_BLK;
        cap &= ~31L;                                   // multiple of NGRP
        if (cap < 32) cap = 32;
        g_nblk = (int)cap;
    }

    pack_weights<<<3215, 256, 0, stream>>>(
        w_i, b_wi, u_i, b_ui, w_f, b_wf, u_f, b_uf,
        w_o, b_wo, u_o, b_uo, w_u, b_wu, u_u, b_uu,
        WfP, Uf, Wz, BZ, Bwf, BUFb, BAR);
    stage_all<<<15360, 256, 0, stream>>>(word_ids, emb, Xall);
    wxf_all_kernel<<<1920, 256, 0, stream>>>(Xall, WfP, Bwf, WXFall);

    float* h_final = (float*)d_out;
    float* c_final = (float*)d_out + (size_t)NN * HH;

    mega<<<g_nblk, 256, 0, stream>>>(
        Xall, WXFall, Wz, BZ, Uf, BUFb, child_idx, child_mask,
        FPbf, HTbf, SCb, Hbf, C0, h_final, c_final, BAR, g_nblk);
}

// Round 2
// 887.937 us; speedup vs baseline: 1.9792x; 1.9792x over previous
//
#include <hip/hip_runtime.h>
#include <cmath>
#include <cstdint>

// ---------------------------------------------------------------------------
// DependencyTreeLSTM — one fused kernel per tree level (13 dispatches total).
// R1 lesson: persistent mega-kernel + software grid barrier = per-barrier L2
// invalidates on 8 non-coherent XCDs -> 833 MB HBM re-fetch, 2.8x regression.
// Here each block owns 16 complete nodes for a level and does EVERYTHING for
// them in one pass (no intra-level grid sync needed):
//   stage X (emb gather, bf16)                 -> LDS
//   WX  = X @ w_f^T + b_wf                     -> LDS   (kills wxf_all GEMM)
//   gather: HT = sum m*h_child                 -> LDS   (kills HTbf round-trip)
//           SC = sum m*sigmoid(WX+FP_ch)*c_ch  -> LDS   (kills SCb round-trip)
//   Z   = [X|HT] @ Wz^T, cell epilogue         -> C, H (global, ping-pong)
//   FP  = h @ u_f^T + b_uf                     -> FPbf (global, ping-pong)
// Cross-level deps (child h/c/FP) are read-only from the previous dispatch;
// ping-pong buffers avoid same-kernel read/write races.
// Grid 256 x 512 thr (8 waves), ~62 KB LDS, 1 block/CU.
// ---------------------------------------------------------------------------

#define NN    4096
#define HH    300
#define KK    8
#define LVLS  12
#define KP    320
#define TPB   512

typedef __bf16  bf16x8 __attribute__((ext_vector_type(8)));
typedef float   f32x4  __attribute__((ext_vector_type(4)));

__device__ __forceinline__ float sigmoidf_(float x) {
    return 1.0f / (1.0f + expf(-x));
}
__device__ __forceinline__ ushort f2bf(float f) {   // f32 -> bf16, RNE
    union { float f; uint32_t u; } v; v.f = f;
    return (ushort)((v.u + 0x7fffu + ((v.u >> 16) & 1u)) >> 16);
}
__device__ __forceinline__ float bf2f(ushort u) {
    union { uint32_t u; float f; } v; v.u = ((uint32_t)u) << 16;
    return v.f;
}

// ---------------------------------------------------------------------------
// Weight packing (bf16, padded):
//   WfP [320][320] = w_f;  Uf [320][320] = u_f;
//   Wz  [3][320][640]  g=[i|o|u], k<320 -> w_g, k>=320 -> u_g;
//   BZ[3][320] = b_wg + b_ug;  Bwf[320] = b_wf;  BUF[320] = b_uf.
// ---------------------------------------------------------------------------
__global__ __launch_bounds__(256)
void pack_weights(
    const float* __restrict__ wi, const float* __restrict__ bwi,
    const float* __restrict__ ui, const float* __restrict__ bui,
    const float* __restrict__ wf, const float* __restrict__ bwf,
    const float* __restrict__ uf, const float* __restrict__ buf_,
    const float* __restrict__ wo, const float* __restrict__ bwo,
    const float* __restrict__ uo, const float* __restrict__ buo,
    const float* __restrict__ wu, const float* __restrict__ bwu,
    const float* __restrict__ uu, const float* __restrict__ buu,
    ushort* __restrict__ WfP, ushort* __restrict__ Uf, ushort* __restrict__ Wz,
    float* __restrict__ BZ, float* __restrict__ Bwf, float* __restrict__ BUF)
{
    int t = blockIdx.x * 256 + threadIdx.x;
    if (t < 102400) {                                    // WfP
        int r = t / KP, k = t % KP;
        WfP[t] = f2bf((r < 300 && k < 300) ? wf[r * 300 + k] : 0.f);
    } else if (t < 204800) {                             // Uf
        int x = t - 102400, r = x / KP, k = x % KP;
        Uf[x] = f2bf((r < 300 && k < 300) ? uf[r * 300 + k] : 0.f);
    } else if (t < 819200) {                             // Wz [3][320][640]
        int x = t - 204800;
        int g = x / 204800, rem = x % 204800;
        int r = rem / 640, k = rem % 640;
        const float* W = (g == 0) ? wi : (g == 1) ? wo : wu;
        const float* U = (g == 0) ? ui : (g == 1) ? uo : uu;
        float v = 0.f;
        if (r < 300) {
            if (k < 320) { if (k < 300) v = W[r * 300 + k]; }
            else         { int kk = k - 320; if (kk < 300) v = U[r * 300 + kk]; }
        }
        Wz[x] = f2bf(v);
    } else if (t < 820160) {                             // BZ [3][320]
        int x = t - 819200, g = x / KP, r = x % KP;
        const float* bw = (g == 0) ? bwi : (g == 1) ? bwo : bwu;
        const float* bu = (g == 0) ? bui : (g == 1) ? buo : buu;
        BZ[x] = (r < 300) ? bw[r] + bu[r] : 0.f;
    } else if (t < 820480) {                             // Bwf
        int r = t - 820160;
        Bwf[r] = (r < 300) ? bwf[r] : 0.f;
    } else if (t < 820800) {                             // BUF
        int r = t - 820480;
        BUF[r] = (r < 300) ? buf_[r] : 0.f;
    }
}

// ---------------------------------------------------------------------------
// Fused level kernel.  Block b owns nodes [16b, 16b+16).  8 waves; wave w
// owns output n-frags {3w, 3w+1, 3w+2} (valid if < 19) for every GEMM phase.
// LDS strides chosen so MFMA ds_read_b128 rows land 2 lanes/bank (free):
// byte-stride/4 % 32 == 4  (A: 648 us, H2/WX: 328 us).
// ---------------------------------------------------------------------------
__global__ __launch_bounds__(512, 1)
void level_fused(const int* __restrict__ wids, const float* __restrict__ emb,
                 const ushort* __restrict__ WfP, const float* __restrict__ Bwf,
                 const ushort* __restrict__ Wz,  const float* __restrict__ BZ,
                 const ushort* __restrict__ Uf,  const float* __restrict__ BUFb,
                 const int* __restrict__ cidx,   const float* __restrict__ cmask,
                 const ushort* __restrict__ Hin, const float* __restrict__ Cin,
                 const ushort* __restrict__ FPin,
                 ushort* __restrict__ Hout, float* __restrict__ Cout,
                 ushort* __restrict__ FPout,      // null at last level
                 float* __restrict__ hdst)        // null except last level
{
    __shared__ __attribute__((aligned(16))) ushort A_lds[16][648]; // X|HT
    __shared__ __attribute__((aligned(16))) float  SC_lds[16][304];
    __shared__ __attribute__((aligned(16))) ushort H2_lds[16][328];
    __shared__ __attribute__((aligned(16))) ushort WX_lds[16][328];
    __shared__ int   ci_lds[16][KK];
    __shared__ float mk_lds[16][KK];

    const int r0g = blockIdx.x * 16;            // global node row base
    const int t = threadIdx.x;
    const int w = t >> 6, l = t & 63;
    const int kq = l >> 4, lr = l & 15;
    const int col = l & 15, rr0 = (l >> 4) * 4;
    const int nfb = w * 3;

    // ---- init: child meta, zero pads, stage X (emb gather -> bf16) ------
    if (t < 128) {
        ci_lds[t >> 3][t & 7] = cidx[(r0g + (t >> 3)) * KK + (t & 7)];
        mk_lds[t >> 3][t & 7] = cmask[(r0g + (t >> 3)) * KK + (t & 7)];
    }
    {
        int z = t - 128;
        if (z >= 0 && z < 320) {                // 16 rows x 20 pad cols
            int zr = z / 20, zc = z % 20;
            A_lds[zr][300 + zc] = 0;            // X k-pad   (300..319)
            A_lds[zr][620 + zc] = 0;            // HT k-pad  (620..639)
            H2_lds[zr][300 + zc] = 0;           // h k-pad
        }
    }
    for (int it = t; it < 1200; it += TPB) {    // 16 rows x 75 f32x4 chunks
        int nr = it / 75, ch = it % 75;
        const float4 v = *reinterpret_cast<const float4*>(
            emb + (size_t)wids[r0g + nr] * HH + ch * 4);
        ushort4 o;
        o.x = f2bf(v.x); o.y = f2bf(v.y); o.z = f2bf(v.z); o.w = f2bf(v.w);
        *reinterpret_cast<ushort4*>(&A_lds[nr][ch * 4]) = o;
    }
    __syncthreads();

    // ---- WX = X @ w_f^T + b_wf  (19 n-frags, K=320) ---------------------
    {
        f32x4 acc[3] = {};
        #pragma unroll 2
        for (int s = 0; s < 10; ++s) {
            const int kk8 = (s * 4 + kq) * 8;
            bf16x8 af = *reinterpret_cast<const bf16x8*>(&A_lds[lr][kk8]);
            #pragma unroll
            for (int i = 0; i < 3; ++i) {
                const int nf = nfb + i;
                if (nf < 19) {
                    bf16x8 bf = *reinterpret_cast<const bf16x8*>(
                        WfP + (size_t)(nf * 16 + lr) * KP + kk8);
                    acc[i] = __builtin_amdgcn_mfma_f32_16x16x32_bf16(
                        af, bf, acc[i], 0, 0, 0);
                }
            }
        }
        #pragma unroll
        for (int i = 0; i < 3; ++i) {
            const int nf = nfb + i;
            if (nf < 19) {
                const int gn = nf * 16 + col;
                if (gn < 300) {
                    const float bb = Bwf[gn];
                    #pragma unroll
                    for (int r = 0; r < 4; ++r)
                        WX_lds[rr0 + r][gn] = f2bf(acc[i][r] + bb);
                }
            }
        }
    }
    __syncthreads();

    // ---- gather: HT -> A_lds[.][320+], SC -> SC_lds ---------------------
    for (int it = t; it < 1200; it += TPB) {
        int nr = it / 75, ch = it % 75;
        const int h0 = ch * 4;
        ushort4 wxu = *reinterpret_cast<const ushort4*>(&WX_lds[nr][h0]);
        const float wx0 = bf2f(wxu.x), wx1 = bf2f(wxu.y),
                    wx2 = bf2f(wxu.z), wx3 = bf2f(wxu.w);
        float ht0 = 0.f, ht1 = 0.f, ht2 = 0.f, ht3 = 0.f;
        float sc0 = 0.f, sc1 = 0.f, sc2 = 0.f, sc3 = 0.f;
        #pragma unroll
        for (int k = 0; k < KK; ++k) {
            const float m = mk_lds[nr][k];
            if (m != 0.f) {
                const size_t cr = (size_t)ci_lds[nr][k];
                ushort4 hu = *reinterpret_cast<const ushort4*>(
                    &Hin[cr * KP + h0]);
                ushort4 fu = *reinterpret_cast<const ushort4*>(
                    &FPin[cr * KP + h0]);
                float4  ck = *reinterpret_cast<const float4*>(
                    &Cin[cr * HH + h0]);
                ht0 += m * bf2f(hu.x); ht1 += m * bf2f(hu.y);
                ht2 += m * bf2f(hu.z); ht3 += m * bf2f(hu.w);
                sc0 += m * sigmoidf_(wx0 + bf2f(fu.x)) * ck.x;
                sc1 += m * sigmoidf_(wx1 + bf2f(fu.y)) * ck.y;
                sc2 += m * sigmoidf_(wx2 + bf2f(fu.z)) * ck.z;
                sc3 += m * sigmoidf_(wx3 + bf2f(fu.w)) * ck.w;
            }
        }
        ushort4 ho;
        ho.x = f2bf(ht0); ho.y = f2bf(ht1); ho.z = f2bf(ht2); ho.w = f2bf(ht3);
        *reinterpret_cast<ushort4*>(&A_lds[nr][320 + h0]) = ho;
        float4 so; so.x = sc0; so.y = sc1; so.z = sc2; so.w = sc3;
        *reinterpret_cast<float4*>(&SC_lds[nr][h0]) = so;
    }
    __syncthreads();

    // ---- gates GEMM: Z = [X|HT] @ Wz^T  (19 nf x 3 gates, K=640) --------
    f32x4 zac[3][3] = {};                       // [nf_i][gate]
    #pragma unroll 2
    for (int s = 0; s < 20; ++s) {
        const int kk8 = (s * 4 + kq) * 8;
        bf16x8 af = *reinterpret_cast<const bf16x8*>(&A_lds[lr][kk8]);
        #pragma unroll
        for (int i = 0; i < 3; ++i) {
            const int nf = nfb + i;
            if (nf < 19) {
                #pragma unroll
                for (int g = 0; g < 3; ++g) {
                    bf16x8 bf = *reinterpret_cast<const bf16x8*>(
                        Wz + ((size_t)g * KP + nf * 16 + lr) * 640 + kk8);
                    zac[i][g] = __builtin_amdgcn_mfma_f32_16x16x32_bf16(
                        af, bf, zac[i][g], 0, 0, 0);
                }
            }
        }
    }

    // ---- cell epilogue --------------------------------------------------
    #pragma unroll
    for (int i = 0; i < 3; ++i) {
        const int nf = nfb + i;
        if (nf < 19) {
            const int gn = nf * 16 + col;
            if (gn < 300) {
                const float bi_ = BZ[gn], bo_ = BZ[KP + gn],
                            bu_ = BZ[2 * KP + gn];
                #pragma unroll
                for (int r = 0; r < 4; ++r) {
                    const int row = rr0 + r;
                    const int gm  = r0g + row;
                    const float sc = SC_lds[row][gn];
                    const float ig = sigmoidf_(zac[i][0][r] + bi_);
                    const float og = sigmoidf_(zac[i][1][r] + bo_);
                    const float ug = tanhf   (zac[i][2][r] + bu_);
                    const float c  = ig * ug + sc;
                    const float hv = og * tanhf(c);
                    Cout[(size_t)gm * HH + gn] = c;
                    const ushort hb = f2bf(hv);
                    Hout[(size_t)gm * KP + gn] = hb;
                    H2_lds[row][gn] = hb;
                    if (hdst) hdst[(size_t)gm * HH + gn] = hv;
                }
            }
        }
    }
    __syncthreads();

    // ---- FP = h @ u_f^T + b_uf for next level (skip at last) ------------
    if (FPout) {
        f32x4 fac[3] = {};
        #pragma unroll 2
        for (int s = 0; s < 10; ++s) {
            const int kk8 = (s * 4 + kq) * 8;
            bf16x8 af = *reinterpret_cast<const bf16x8*>(&H2_lds[lr][kk8]);
            #pragma unroll
            for (int i = 0; i < 3; ++i) {
                const int nf = nfb + i;
                if (nf < 19) {
                    bf16x8 bf = *reinterpret_cast<const bf16x8*>(
                        Uf + (size_t)(nf * 16 + lr) * KP + kk8);
                    fac[i] = __builtin_amdgcn_mfma_f32_16x16x32_bf16(
                        af, bf, fac[i], 0, 0, 0);
                }
            }
        }
        #pragma unroll
        for (int i = 0; i < 3; ++i) {
            const int nf = nfb + i;
            if (nf < 19) {
                const int gn = nf * 16 + col;
                if (gn < 300) {
                    const float bb = BUFb[gn];
                    #pragma unroll
                    for (int r = 0; r < 4; ++r)
                        FPout[(size_t)(r0g + rr0 + r) * KP + gn] =
                            f2bf(fac[i][r] + bb);
                }
            }
        }
    }
}

// ---------------------------------------------------------------------------
extern "C" void kernel_launch(void* const* d_in, const int* in_sizes, int n_in,
                              void* d_out, int out_size, void* d_ws, size_t ws_size,
                              hipStream_t stream)
{
    const int*   word_ids   = (const int*)  d_in[0];
    const int*   child_idx  = (const int*)  d_in[1];
    const float* child_mask = (const float*)d_in[2];
    const float* emb        = (const float*)d_in[3];
    const float* w_i  = (const float*)d_in[4];  const float* b_wi = (const float*)d_in[5];
    const float* u_i  = (const float*)d_in[6];  const float* b_ui = (const float*)d_in[7];
    const float* w_f  = (const float*)d_in[8];  const float* b_wf = (const float*)d_in[9];
    const float* u_f  = (const float*)d_in[10]; const float* b_uf = (const float*)d_in[11];
    const float* w_o  = (const float*)d_in[12]; const float* b_wo = (const float*)d_in[13];
    const float* u_o  = (const float*)d_in[14]; const float* b_uo = (const float*)d_in[15];
    const float* w_u  = (const float*)d_in[16]; const float* b_wu = (const float*)d_in[17];
    const float* u_u  = (const float*)d_in[18]; const float* b_uu = (const float*)d_in[19];

    uint8_t* ws = (uint8_t*)d_ws;
    size_t off = 0;
    auto alloc = [&](size_t bytes) {
        uint8_t* p = ws + off;
        off += (bytes + 255) & ~(size_t)255;
        return p;
    };
    ushort* WfP  = (ushort*)alloc((size_t)KP * KP * 2);
    ushort* Uf   = (ushort*)alloc((size_t)KP * KP * 2);
    ushort* Wz   = (ushort*)alloc((size_t)3 * KP * 640 * 2);
    ushort* Hb0  = (ushort*)alloc((size_t)NN * KP * 2);
    ushort* Hb1  = (ushort*)alloc((size_t)NN * KP * 2);
    float*  Cb0  = (float*) alloc((size_t)NN * HH * 4);
    float*  Cb1  = (float*) alloc((size_t)NN * HH * 4);
    ushort* FP0  = (ushort*)alloc((size_t)NN * KP * 2);
    ushort* FP1  = (ushort*)alloc((size_t)NN * KP * 2);
    float*  BZ   = (float*) alloc(3 * KP * 4);
    float*  Bwf  = (float*) alloc(KP * 4);
    float*  BUFb = (float*) alloc(KP * 4);

    ushort* Hb[2] = { Hb0, Hb1 };
    float*  Cb[2] = { Cb0, Cb1 };
    ushort* FPb[2] = { FP0, FP1 };

    pack_weights<<<3207, 256, 0, stream>>>(
        w_i, b_wi, u_i, b_ui, w_f, b_wf, u_f, b_uf,
        w_o, b_wo, u_o, b_uo, w_u, b_wu, u_u, b_uu,
        WfP, Uf, Wz, BZ, Bwf, BUFb);

    float* h_final = (float*)d_out;
    float* c_final = (float*)d_out + (size_t)NN * HH;

    int cur = 0;
    for (int lev = 0; lev < LVLS; ++lev) {
        const bool last = (lev == LVLS - 1);
        level_fused<<<256, 512, 0, stream>>>(
            word_ids + (size_t)lev * NN, emb, WfP, Bwf, Wz, BZ, Uf, BUFb,
            child_idx + (size_t)lev * NN * KK,
            child_mask + (size_t)lev * NN * KK,
            Hb[cur], Cb[cur], FPb[cur],
            Hb[cur ^ 1], last ? c_final : Cb[cur ^ 1],
            last ? (ushort*)nullptr : FPb[cur ^ 1],
            last ? h_final : nullptr);
        cur ^= 1;
    }
}

// Round 3
// 673.237 us; speedup vs baseline: 2.6103x; 1.3189x over previous
//
#include <hip/hip_runtime.h>
#include <cmath>
#include <cstdint>

// ---------------------------------------------------------------------------
// DependencyTreeLSTM, concat-K + register-direct skinny GEMMs (R0 structure).
// R1 (persistent mega + grid barrier): 2.8x regression — agent-scope barrier
// fences force L2 invalidates on 8 non-coherent XCDs -> 833 MB HBM refetch.
// R2 (one fused kernel/level): 1.4x regression — grid capped at 256 blocks
// (4096 nodes / 16 rows), 1 block/CU, gather phase latency-bound at 8
// waves/CU (MfmaUtil 2.6%, 440 GB/s).
// This round: R0 split-kernel structure + (1) branchless prefetched child
// gather in reduce (MLP), (2) zcell LDS reduce 48->36 KB (own m-frag in
// regs, verified in R1) -> 4 blocks/CU, (3) pack+stage merged.
// ---------------------------------------------------------------------------

#define NN    4096
#define HH    300
#define KK    8
#define LVLS  12
#define KP    320

typedef __bf16  bf16x8 __attribute__((ext_vector_type(8)));
typedef float   f32x4  __attribute__((ext_vector_type(4)));

#define GAS __attribute__((address_space(1)))
#define LAS __attribute__((address_space(3)))

__device__ __forceinline__ float sigmoidf_(float x) {
    return 1.0f / (1.0f + expf(-x));
}
__device__ __forceinline__ ushort f2bf(float f) {   // f32 -> bf16, RNE
    union { float f; uint32_t u; } v; v.f = f;
    return (ushort)((v.u + 0x7fffu + ((v.u >> 16) & 1u)) >> 16);
}
__device__ __forceinline__ float bf2f(ushort u) {
    union { uint32_t u; float f; } v; v.u = ((uint32_t)u) << 16;
    return v.f;
}

// ---------------------------------------------------------------------------
// Weight packing (bf16, padded) + X staging, one dispatch.
//   blocks [0, 3207):      pack  (WfP, Uf, Wz, BZ, Bwf, BUF)
//   blocks [3207, 18567):  stage (X for all 12 levels)
// ---------------------------------------------------------------------------
__global__ __launch_bounds__(256)
void pack_and_stage(
    const float* __restrict__ wi, const float* __restrict__ bwi,
    const float* __restrict__ ui, const float* __restrict__ bui,
    const float* __restrict__ wf, const float* __restrict__ bwf,
    const float* __restrict__ uf, const float* __restrict__ buf_,
    const float* __restrict__ wo, const float* __restrict__ bwo,
    const float* __restrict__ uo, const float* __restrict__ buo,
    const float* __restrict__ wu, const float* __restrict__ bwu,
    const float* __restrict__ uu, const float* __restrict__ buu,
    ushort* __restrict__ WfP, ushort* __restrict__ Uf, ushort* __restrict__ Wz,
    float* __restrict__ BZ, float* __restrict__ Bwf, float* __restrict__ BUF,
    const int* __restrict__ word_ids, const float* __restrict__ emb,
    ushort* __restrict__ X)
{
    const int b = blockIdx.x;
    if (b >= 3207) {                                     // ---- stage part
        int idx = (b - 3207) * 256 + threadIdx.x;        // 12*4096*80
        int nl = idx / 80, kc = idx % 80, k = kc * 4;
        ushort4 o;
        if (kc < 75) {
            const float2* p = reinterpret_cast<const float2*>(
                emb + (size_t)word_ids[nl] * 300 + k);
            float2 v0 = p[0], v1 = p[1];
            o.x = f2bf(v0.x); o.y = f2bf(v0.y); o.z = f2bf(v1.x); o.w = f2bf(v1.y);
        } else {
            o.x = o.y = o.z = o.w = 0;
        }
        *reinterpret_cast<ushort4*>(X + (size_t)nl * KP + k) = o;
        return;
    }
    int t = b * 256 + threadIdx.x;                       // ---- pack part
    if (t < 102400) {                                    // WfP
        int r = t / KP, k = t % KP;
        WfP[t] = f2bf((r < 300 && k < 300) ? wf[r * 300 + k] : 0.f);
    } else if (t < 204800) {                             // Uf
        int x = t - 102400, r = x / KP, k = x % KP;
        Uf[x] = f2bf((r < 300 && k < 300) ? uf[r * 300 + k] : 0.f);
    } else if (t < 819200) {                             // Wz [3][320][640]
        int x = t - 204800;
        int g = x / 204800, rem = x % 204800;
        int r = rem / 640, k = rem % 640;
        const float* W = (g == 0) ? wi : (g == 1) ? wo : wu;
        const float* U = (g == 0) ? ui : (g == 1) ? uo : uu;
        float v = 0.f;
        if (r < 300) {
            if (k < 320) { if (k < 300) v = W[r * 300 + k]; }
            else         { int kk = k - 320; if (kk < 300) v = U[r * 300 + kk]; }
        }
        Wz[x] = f2bf(v);
    } else if (t < 820160) {                             // BZ [3][320]
        int x = t - 819200, g = x / KP, r = x % KP;
        const float* bw = (g == 0) ? bwi : (g == 1) ? bwo : bwu;
        const float* bu = (g == 0) ? bui : (g == 1) ? buo : buu;
        BZ[x] = (r < 300) ? bw[r] + bu[r] : 0.f;
    } else if (t < 820480) {                             // Bwf
        int r = t - 820160;
        Bwf[r] = (r < 300) ? bwf[r] : 0.f;
    } else if (t < 820800) {                             // BUF
        int r = t - 820480;
        BUF[r] = (r < 300) ? buf_[r] : 0.f;
    }
}

// ---------------------------------------------------------------------------
// 128x64 G=1 GEMM core (4 waves 2x2, wave 64x32) - for the big WXF_all GEMM.
// ---------------------------------------------------------------------------
template <int NSTEP>
__device__ __forceinline__
void gemm128_core(const ushort* __restrict__ A, const ushort* __restrict__ B,
                  int m0, int n0,
                  ushort (&As)[4][128][8], ushort (&Bs)[4][64][8],
                  f32x4 (&acc)[4][2])
{
    const int t  = threadIdx.x;
    const int l  = t & 63, w = t >> 6;
    const int m_off = (w >> 1) * 64, n_off = (w & 1) * 32;
    const int kq = l >> 4, lr = l & 15;
    const int arow = t & 127, akb0 = t >> 7;
    const int brow = t & 63,  bkb  = t >> 6;

    for (int s = 0; s < NSTEP; ++s) {
        #pragma unroll
        for (int c = 0; c < 2; ++c) {
            const int akb = akb0 + c * 2;
            const int kc  = s * 4 + akb;
            const ushort* ga = A + (size_t)(m0 + arow) * KP + (size_t)kc * 8;
            __builtin_amdgcn_global_load_lds((const GAS void*)ga,
                (LAS void*)&As[akb][arow][0], 16, 0, 0);
        }
        {
            const int kc = s * 4 + bkb;
            const ushort* gb = B + (size_t)(n0 + brow) * KP + (size_t)kc * 8;
            __builtin_amdgcn_global_load_lds((const GAS void*)gb,
                (LAS void*)&Bs[bkb][brow][0], 16, 0, 0);
        }
        __syncthreads();

        bf16x8 af[4], bfr[2];
        #pragma unroll
        for (int mi = 0; mi < 4; ++mi)
            af[mi] = *reinterpret_cast<const bf16x8*>(
                &As[kq][m_off + mi * 16 + lr][0]);
        #pragma unroll
        for (int ni = 0; ni < 2; ++ni)
            bfr[ni] = *reinterpret_cast<const bf16x8*>(
                &Bs[kq][n_off + ni * 16 + lr][0]);
        #pragma unroll
        for (int mi = 0; mi < 4; ++mi)
            #pragma unroll
            for (int ni = 0; ni < 2; ++ni)
                acc[mi][ni] = __builtin_amdgcn_mfma_f32_16x16x32_bf16(
                    af[mi], bfr[ni], acc[mi][ni], 0, 0, 0);
        __syncthreads();
    }
}

// WXF_all = X_all[49152][320] @ w_f^T + b_wf -> bf16 [49152][320].  Grid 1920.
__global__ __launch_bounds__(256)
void wxf_all_kernel(const ushort* __restrict__ Xall, const ushort* __restrict__ WfP,
                    const float* __restrict__ Bwf, ushort* __restrict__ WXFall)
{
    __shared__ __attribute__((aligned(16))) ushort As[4][128][8];
    __shared__ __attribute__((aligned(16))) ushort Bs[4][64][8];

    const int b  = blockIdx.x;
    const int bj = (b % 8) * 240 + b / 8;         // bijective (1920 % 8 == 0)
    const int m0 = (bj / 5) * 128, n0 = (bj % 5) * 64;

    f32x4 acc[4][2] = {};
    gemm128_core<10>(Xall, WfP, m0, n0, As, Bs, acc);

    const int t = threadIdx.x, l = t & 63, w = t >> 6;
    const int m_off = (w >> 1) * 64, n_off = (w & 1) * 32;
    const int col = l & 15, r0 = (l >> 4) * 4;
    #pragma unroll
    for (int mi = 0; mi < 4; ++mi) {
        #pragma unroll
        for (int ni = 0; ni < 2; ++ni) {
            const int gn = n0 + n_off + ni * 16 + col;
            const float bb = Bwf[gn];
            #pragma unroll
            for (int r = 0; r < 4; ++r) {
                const int gm = m0 + m_off + mi * 16 + r0 + r;
                WXFall[(size_t)gm * KP + gn] = f2bf(acc[mi][ni][r] + bb);
            }
        }
    }
}

__device__ __forceinline__ int swz640(int b) { return (b % 8) * 80 + b / 8; }

// ---------------------------------------------------------------------------
// FP = Hbf @ u_f^T + b_uf  (bf16 out, [4096][320]).  Grid 640 x 128 thr.
// Register-direct: lane (kq,lr) loads its own 16B fragments; no LDS/barriers.
// ---------------------------------------------------------------------------
__global__ __launch_bounds__(128)
void fp_kernel(const ushort* __restrict__ Hbf, const ushort* __restrict__ Uf,
               const float* __restrict__ BUF, ushort* __restrict__ FP)
{
    const int bj = swz640((int)blockIdx.x);
    const int m0 = (bj / 10) * 64, n0 = (bj % 10) * 32;
    const int t = threadIdx.x, w = t >> 6, l = t & 63;
    const int kq = l >> 4, lr = l & 15, m_off = w * 32;

    f32x4 acc[2][2] = {};
    #pragma unroll
    for (int s = 0; s < 10; ++s) {
        const int kc = s * 4 + kq;
        bf16x8 af[2], bfr[2];
        #pragma unroll
        for (int mi = 0; mi < 2; ++mi)
            af[mi] = *reinterpret_cast<const bf16x8*>(
                Hbf + (size_t)(m0 + m_off + mi * 16 + lr) * KP + (size_t)kc * 8);
        #pragma unroll
        for (int ni = 0; ni < 2; ++ni)
            bfr[ni] = *reinterpret_cast<const bf16x8*>(
                Uf + (size_t)(n0 + ni * 16 + lr) * KP + (size_t)kc * 8);
        #pragma unroll
        for (int mi = 0; mi < 2; ++mi)
            #pragma unroll
            for (int ni = 0; ni < 2; ++ni)
                acc[mi][ni] = __builtin_amdgcn_mfma_f32_16x16x32_bf16(
                    af[mi], bfr[ni], acc[mi][ni], 0, 0, 0);
    }

    const int col = l & 15, r0 = (l >> 4) * 4;
    #pragma unroll
    for (int mi = 0; mi < 2; ++mi) {
        #pragma unroll
        for (int ni = 0; ni < 2; ++ni) {
            const int gn = n0 + ni * 16 + col;
            const float bb = BUF[gn];
            #pragma unroll
            for (int r = 0; r < 4; ++r) {
                const int gm = m0 + m_off + mi * 16 + r0 + r;
                FP[(size_t)gm * KP + gn] = f2bf(acc[mi][ni][r] + bb);
            }
        }
    }
}

// ---------------------------------------------------------------------------
// Child gather + masked sums.  4 nodes/block, vectorized.
// Loads are UNCONDITIONAL and prefetched (MLP); math stays masked.  Indices
// are always valid; level-0 garbage data is masked out (mask==0 everywhere).
// ---------------------------------------------------------------------------
__global__ __launch_bounds__(320)
void reduce_kernel(const ushort* __restrict__ Hbf, const float* __restrict__ Cst,
                   const ushort* __restrict__ FP, const ushort* __restrict__ WXF,
                   const int* __restrict__ cidx, const float* __restrict__ cmask,
                   ushort* __restrict__ HT, float* __restrict__ SC)
{
    const int x = threadIdx.x;          // 0..79
    const int ty = threadIdx.y;         // 0..3
    const int n = blockIdx.x * 4 + ty;
    __shared__ int   ch[4][KK];
    __shared__ float mk[4][KK];
    if (x < KK) {
        ch[ty][x] = cidx[n * KK + x];
        mk[ty][x] = cmask[n * KK + x];
    }
    __syncthreads();
    if (x >= 75) return;
    const int h = x * 4;

    // prefetch all child rows (branchless -> max loads in flight)
    ushort4 hu[KK]; ushort4 fu[KK]; float4 cv[KK];
    #pragma unroll
    for (int k = 0; k < KK; ++k) {
        const size_t cr = (size_t)ch[ty][k];
        hu[k] = *reinterpret_cast<const ushort4*>(&Hbf[cr * KP + h]);
        fu[k] = *reinterpret_cast<const ushort4*>(&FP [cr * KP + h]);
        cv[k] = *reinterpret_cast<const float4*>(&Cst[cr * HH + h]);
    }

    ushort4 wxu = *reinterpret_cast<const ushort4*>(&WXF[(size_t)n * KP + h]);
    const float wx0 = bf2f(wxu.x), wx1 = bf2f(wxu.y),
                wx2 = bf2f(wxu.z), wx3 = bf2f(wxu.w);
    float ht0 = 0.f, ht1 = 0.f, ht2 = 0.f, ht3 = 0.f;
    float sc0 = 0.f, sc1 = 0.f, sc2 = 0.f, sc3 = 0.f;

    #pragma unroll
    for (int k = 0; k < KK; ++k) {
        const float m = mk[ty][k];
        if (m != 0.f) {                 // wave-mostly-uniform (per-node mask)
            ht0 += m * bf2f(hu[k].x); ht1 += m * bf2f(hu[k].y);
            ht2 += m * bf2f(hu[k].z); ht3 += m * bf2f(hu[k].w);
            sc0 += m * sigmoidf_(wx0 + bf2f(fu[k].x)) * cv[k].x;
            sc1 += m * sigmoidf_(wx1 + bf2f(fu[k].y)) * cv[k].y;
            sc2 += m * sigmoidf_(wx2 + bf2f(fu[k].z)) * cv[k].z;
            sc3 += m * sigmoidf_(wx3 + bf2f(fu[k].w)) * cv[k].w;
        }
    }
    ushort4 ho; ho.x = f2bf(ht0); ho.y = f2bf(ht1); ho.z = f2bf(ht2); ho.w = f2bf(ht3);
    *reinterpret_cast<ushort4*>(&HT[(size_t)n * KP + h]) = ho;
    float4 so; so.x = sc0; so.y = sc1; so.z = sc2; so.w = sc3;
    *reinterpret_cast<float4*>(&SC[(size_t)n * KP + h]) = so;
}

// ---------------------------------------------------------------------------
// zcell, register-direct wave-split-K: grid 1216 (64 m-tiles x 19 n-tiles),
// 256 threads.  Block tile 64 rows x 16 cols x 3 gates; wave w owns global
// K range [w*160, w*160+160): waves 0-1 read X, waves 2-3 read HT; Wz always
// indexed by GLOBAL k.  Fragments loaded straight to VGPRs (no LDS staging,
// no K-loop barriers).  LDS only for the cross-wave split-K reduce: 36 KB
// (each wave keeps its OWN m-frag in registers, publishes the other 9) ->
// 4 blocks/CU co-resident.  Fused cell epilogue.
// ---------------------------------------------------------------------------
__global__ __launch_bounds__(256)
void zcell(const ushort* __restrict__ X, const ushort* __restrict__ HT,
           const ushort* __restrict__ Wz, const float* __restrict__ BZ,
           const float* __restrict__ SC,
           float* __restrict__ cdst, ushort* __restrict__ Hb,
           float* __restrict__ hdst)
{
    __shared__ __attribute__((aligned(16))) f32x4 red[4][9][64];   // 36 KB

    const int b  = blockIdx.x;
    const int bj = (b & 7) * 152 + (b >> 3);      // bijective, 1216 = 8*152
    const int m0 = (bj / 19) * 64, n0 = (bj % 19) * 16;

    const int t  = threadIdx.x;
    const int w  = t >> 6, l = t & 63;
    const int kq = l >> 4, lr = l & 15;

    const ushort* Abase = (w < 2) ? X : HT;
    const int akb0 = (w < 2) ? (w * 20) : (w * 20 - 40);  // A-local k-chunk
    const int gkb0 = w * 20;                              // GLOBAL k-chunk

    f32x4 acc[3][4] = {};

    #pragma unroll
    for (int s = 0; s < 5; ++s) {
        const int kA = akb0 + s * 4 + kq;
        const int kB = gkb0 + s * 4 + kq;
        bf16x8 af[4], bfr[3];
        #pragma unroll
        for (int mi = 0; mi < 4; ++mi)
            af[mi] = *reinterpret_cast<const bf16x8*>(
                Abase + (size_t)(m0 + mi * 16 + lr) * KP + (size_t)kA * 8);
        #pragma unroll
        for (int g = 0; g < 3; ++g)
            bfr[g] = *reinterpret_cast<const bf16x8*>(
                Wz + ((size_t)g * KP + n0 + lr) * 640 + (size_t)kB * 8);
        #pragma unroll
        for (int g = 0; g < 3; ++g)
            #pragma unroll
            for (int mi = 0; mi < 4; ++mi)
                acc[g][mi] = __builtin_amdgcn_mfma_f32_16x16x32_bf16(
                    af[mi], bfr[g], acc[g][mi], 0, 0, 0);
    }

    // ---- cross-wave split-K reduce (own m-frag stays in registers) ----
    f32x4 own[3];
    #pragma unroll
    for (int g = 0; g < 3; ++g) {
        #pragma unroll
        for (int mi = 0; mi < 4; ++mi) {
            if (mi != w)
                red[w][g * 3 + mi - (mi > w)][l] = acc[g][mi];
            else
                own[g] = acc[g][mi];
        }
    }
    __syncthreads();

    const int gn = n0 + lr;
    if (gn < 300) {
        f32x4 sg[3];
        #pragma unroll
        for (int g = 0; g < 3; ++g) {
            f32x4 v = own[g];
            #pragma unroll
            for (int sw = 0; sw < 4; ++sw) {
                if (sw != w) {
                    f32x4 u2 = red[sw][g * 3 + w - (w > sw)][l];
                    v[0] += u2[0]; v[1] += u2[1]; v[2] += u2[2]; v[3] += u2[3];
                }
            }
            sg[g] = v;
        }
        const float bi_ = BZ[gn], bo_ = BZ[KP + gn], bu_ = BZ[2 * KP + gn];
        const int gmb = m0 + w * 16 + (l >> 4) * 4;
        #pragma unroll
        for (int r = 0; r < 4; ++r) {
            const int gm = gmb + r;
            float sc = SC[(size_t)gm * KP + gn];
            float ig = sigmoidf_(sg[0][r] + bi_);
            float og = sigmoidf_(sg[1][r] + bo_);
            float ug = tanhf   (sg[2][r] + bu_);
            float c  = ig * ug + sc;
            float hv = og * tanhf(c);
            cdst[(size_t)gm * HH + gn] = c;
            Hb  [(size_t)gm * KP + gn] = f2bf(hv);
            if (hdst) hdst[(size_t)gm * HH + gn] = hv;
        }
    }
}

// ---------------------------------------------------------------------------
extern "C" void kernel_launch(void* const* d_in, const int* in_sizes, int n_in,
                              void* d_out, int out_size, void* d_ws, size_t ws_size,
                              hipStream_t stream)
{
    const int*   word_ids   = (const int*)  d_in[0];
    const int*   child_idx  = (const int*)  d_in[1];
    const float* child_mask = (const float*)d_in[2];
    const float* emb        = (const float*)d_in[3];
    const float* w_i  = (const float*)d_in[4];  const float* b_wi = (const float*)d_in[5];
    const float* u_i  = (const float*)d_in[6];  const float* b_ui = (const float*)d_in[7];
    const float* w_f  = (const float*)d_in[8];  const float* b_wf = (const float*)d_in[9];
    const float* u_f  = (const float*)d_in[10]; const float* b_uf = (const float*)d_in[11];
    const float* w_o  = (const float*)d_in[12]; const float* b_wo = (const float*)d_in[13];
    const float* u_o  = (const float*)d_in[14]; const float* b_uo = (const float*)d_in[15];
    const float* w_u  = (const float*)d_in[16]; const float* b_wu = (const float*)d_in[17];
    const float* u_u  = (const float*)d_in[18]; const float* b_uu = (const float*)d_in[19];

    uint8_t* ws = (uint8_t*)d_ws;
    size_t off = 0;
    auto alloc = [&](size_t bytes) {
        uint8_t* p = ws + off;
        off += (bytes + 255) & ~(size_t)255;
        return p;
    };
    ushort* WfP   = (ushort*)alloc((size_t)KP * KP * 2);
    ushort* Uf    = (ushort*)alloc((size_t)KP * KP * 2);
    ushort* Wz    = (ushort*)alloc((size_t)3 * KP * 640 * 2);
    ushort* Xall  = (ushort*)alloc((size_t)LVLS * NN * KP * 2);
    ushort* WXFall= (ushort*)alloc((size_t)LVLS * NN * KP * 2);
    ushort* FPbf  = (ushort*)alloc((size_t)NN * KP * 2);
    ushort* HTbf  = (ushort*)alloc((size_t)NN * KP * 2);
    ushort* Hbf   = (ushort*)alloc((size_t)NN * KP * 2);
    float*  SCb   = (float*) alloc((size_t)NN * KP * 4);
    float*  C0    = (float*) alloc((size_t)NN * HH * 4);
    float*  BZ    = (float*) alloc(3 * KP * 4);
    float*  Bwf   = (float*) alloc(KP * 4);
    float*  BUFb  = (float*) alloc(KP * 4);

    pack_and_stage<<<18567, 256, 0, stream>>>(
        w_i, b_wi, u_i, b_ui, w_f, b_wf, u_f, b_uf,
        w_o, b_wo, u_o, b_uo, w_u, b_wu, u_u, b_uu,
        WfP, Uf, Wz, BZ, Bwf, BUFb,
        word_ids, emb, Xall);
    wxf_all_kernel<<<1920, 256, 0, stream>>>(Xall, WfP, Bwf, WXFall);

    float* h_final = (float*)d_out;
    float* c_final = (float*)d_out + (size_t)NN * HH;

    for (int lev = 0; lev < LVLS; ++lev) {
        const int*    cidx  = child_idx  + (size_t)lev * NN * KK;
        const float*  cmask = child_mask + (size_t)lev * NN * KK;
        const ushort* Xlev  = Xall   + (size_t)lev * NN * KP;
        const ushort* WXFlev= WXFall + (size_t)lev * NN * KP;
        const bool last = (lev == LVLS - 1);
        float* cdst = last ? c_final : C0;
        float* hdst = last ? h_final : nullptr;

        if (lev > 0)
            fp_kernel<<<640, 128, 0, stream>>>(Hbf, Uf, BUFb, FPbf);
        reduce_kernel<<<1024, dim3(80, 4), 0, stream>>>(
            Hbf, C0, FPbf, WXFlev, cidx, cmask, HTbf, SCb);
        zcell<<<1216, 256, 0, stream>>>(
            Xlev, HTbf, Wz, BZ, SCb, cdst, Hbf, hdst);
    }
}

// Round 4
// 642.723 us; speedup vs baseline: 2.7343x; 1.0475x over previous
//
#include <hip/hip_runtime.h>
#include <cmath>
#include <cstdint>

// ---------------------------------------------------------------------------
// DependencyTreeLSTM (R4).  Lesson history:
//  R1 persistent+grid-barrier: L2 invalidates on 8 XCDs -> 2.8x regression.
//  R2 fused level kernel: grid capped at 256 blocks -> latency-bound.
//  R3: zcell (register-direct split-K) exposed as THE cost: ~45us x 12 =
//      ~500us, MfmaUtil 3.5%, latency-serialized loads (VGPR-bound MLP).
//  R4: zcell -> zgemm: global_load_lds-staged GEMM (DMA staging, no VGPR
//      round-trip, proven in wxf_all at ~3.5us/level-equivalent).  Tile =
//      64 rows x 32 j-cols x 3 gates so the cell epilogue fuses (all three
//      gate pre-activations present per output element).  Grid 640, all
//      co-resident, 20 K-steps over concat K=640 ([X|HT] splits at s=10,
//      wave-uniform).  Everything else unchanged from R3.
// ---------------------------------------------------------------------------

#define NN    4096
#define HH    300
#define KK    8
#define LVLS  12
#define KP    320

typedef __bf16  bf16x8 __attribute__((ext_vector_type(8)));
typedef float   f32x4  __attribute__((ext_vector_type(4)));

#define GAS __attribute__((address_space(1)))
#define LAS __attribute__((address_space(3)))

__device__ __forceinline__ float sigmoidf_(float x) {
    return 1.0f / (1.0f + expf(-x));
}
__device__ __forceinline__ ushort f2bf(float f) {   // f32 -> bf16, RNE
    union { float f; uint32_t u; } v; v.f = f;
    return (ushort)((v.u + 0x7fffu + ((v.u >> 16) & 1u)) >> 16);
}
__device__ __forceinline__ float bf2f(ushort u) {
    union { uint32_t u; float f; } v; v.u = ((uint32_t)u) << 16;
    return v.f;
}

// ---------------------------------------------------------------------------
// Weight packing (bf16, padded) + X staging, one dispatch.
//   blocks [0, 3207):      pack  (WfP, Uf, Wz, BZ, Bwf, BUF)
//   blocks [3207, 18567):  stage (X for all 12 levels)
// ---------------------------------------------------------------------------
__global__ __launch_bounds__(256)
void pack_and_stage(
    const float* __restrict__ wi, const float* __restrict__ bwi,
    const float* __restrict__ ui, const float* __restrict__ bui,
    const float* __restrict__ wf, const float* __restrict__ bwf,
    const float* __restrict__ uf, const float* __restrict__ buf_,
    const float* __restrict__ wo, const float* __restrict__ bwo,
    const float* __restrict__ uo, const float* __restrict__ buo,
    const float* __restrict__ wu, const float* __restrict__ bwu,
    const float* __restrict__ uu, const float* __restrict__ buu,
    ushort* __restrict__ WfP, ushort* __restrict__ Uf, ushort* __restrict__ Wz,
    float* __restrict__ BZ, float* __restrict__ Bwf, float* __restrict__ BUF,
    const int* __restrict__ word_ids, const float* __restrict__ emb,
    ushort* __restrict__ X)
{
    const int b = blockIdx.x;
    if (b >= 3207) {                                     // ---- stage part
        int idx = (b - 3207) * 256 + threadIdx.x;        // 12*4096*80
        int nl = idx / 80, kc = idx % 80, k = kc * 4;
        ushort4 o;
        if (kc < 75) {
            const float2* p = reinterpret_cast<const float2*>(
                emb + (size_t)word_ids[nl] * 300 + k);
            float2 v0 = p[0], v1 = p[1];
            o.x = f2bf(v0.x); o.y = f2bf(v0.y); o.z = f2bf(v1.x); o.w = f2bf(v1.y);
        } else {
            o.x = o.y = o.z = o.w = 0;
        }
        *reinterpret_cast<ushort4*>(X + (size_t)nl * KP + k) = o;
        return;
    }
    int t = b * 256 + threadIdx.x;                       // ---- pack part
    if (t < 102400) {                                    // WfP
        int r = t / KP, k = t % KP;
        WfP[t] = f2bf((r < 300 && k < 300) ? wf[r * 300 + k] : 0.f);
    } else if (t < 204800) {                             // Uf
        int x = t - 102400, r = x / KP, k = x % KP;
        Uf[x] = f2bf((r < 300 && k < 300) ? uf[r * 300 + k] : 0.f);
    } else if (t < 819200) {                             // Wz [3][320][640]
        int x = t - 204800;
        int g = x / 204800, rem = x % 204800;
        int r = rem / 640, k = rem % 640;
        const float* W = (g == 0) ? wi : (g == 1) ? wo : wu;
        const float* U = (g == 0) ? ui : (g == 1) ? uo : uu;
        float v = 0.f;
        if (r < 300) {
            if (k < 320) { if (k < 300) v = W[r * 300 + k]; }
            else         { int kk = k - 320; if (kk < 300) v = U[r * 300 + kk]; }
        }
        Wz[x] = f2bf(v);
    } else if (t < 820160) {                             // BZ [3][320]
        int x = t - 819200, g = x / KP, r = x % KP;
        const float* bw = (g == 0) ? bwi : (g == 1) ? bwo : bwu;
        const float* bu = (g == 0) ? bui : (g == 1) ? buo : buu;
        BZ[x] = (r < 300) ? bw[r] + bu[r] : 0.f;
    } else if (t < 820480) {                             // Bwf
        int r = t - 820160;
        Bwf[r] = (r < 300) ? bwf[r] : 0.f;
    } else if (t < 820800) {                             // BUF
        int r = t - 820480;
        BUF[r] = (r < 300) ? buf_[r] : 0.f;
    }
}

// ---------------------------------------------------------------------------
// 128x64 G=1 GEMM core (4 waves 2x2, wave 64x32) - for the big WXF_all GEMM.
// ---------------------------------------------------------------------------
template <int NSTEP>
__device__ __forceinline__
void gemm128_core(const ushort* __restrict__ A, const ushort* __restrict__ B,
                  int m0, int n0,
                  ushort (&As)[4][128][8], ushort (&Bs)[4][64][8],
                  f32x4 (&acc)[4][2])
{
    const int t  = threadIdx.x;
    const int l  = t & 63, w = t >> 6;
    const int m_off = (w >> 1) * 64, n_off = (w & 1) * 32;
    const int kq = l >> 4, lr = l & 15;
    const int arow = t & 127, akb0 = t >> 7;
    const int brow = t & 63,  bkb  = t >> 6;

    for (int s = 0; s < NSTEP; ++s) {
        #pragma unroll
        for (int c = 0; c < 2; ++c) {
            const int akb = akb0 + c * 2;
            const int kc  = s * 4 + akb;
            const ushort* ga = A + (size_t)(m0 + arow) * KP + (size_t)kc * 8;
            __builtin_amdgcn_global_load_lds((const GAS void*)ga,
                (LAS void*)&As[akb][arow][0], 16, 0, 0);
        }
        {
            const int kc = s * 4 + bkb;
            const ushort* gb = B + (size_t)(n0 + brow) * KP + (size_t)kc * 8;
            __builtin_amdgcn_global_load_lds((const GAS void*)gb,
                (LAS void*)&Bs[bkb][brow][0], 16, 0, 0);
        }
        __syncthreads();

        bf16x8 af[4], bfr[2];
        #pragma unroll
        for (int mi = 0; mi < 4; ++mi)
            af[mi] = *reinterpret_cast<const bf16x8*>(
                &As[kq][m_off + mi * 16 + lr][0]);
        #pragma unroll
        for (int ni = 0; ni < 2; ++ni)
            bfr[ni] = *reinterpret_cast<const bf16x8*>(
                &Bs[kq][n_off + ni * 16 + lr][0]);
        #pragma unroll
        for (int mi = 0; mi < 4; ++mi)
            #pragma unroll
            for (int ni = 0; ni < 2; ++ni)
                acc[mi][ni] = __builtin_amdgcn_mfma_f32_16x16x32_bf16(
                    af[mi], bfr[ni], acc[mi][ni], 0, 0, 0);
        __syncthreads();
    }
}

// WXF_all = X_all[49152][320] @ w_f^T + b_wf -> bf16 [49152][320].  Grid 1920.
__global__ __launch_bounds__(256)
void wxf_all_kernel(const ushort* __restrict__ Xall, const ushort* __restrict__ WfP,
                    const float* __restrict__ Bwf, ushort* __restrict__ WXFall)
{
    __shared__ __attribute__((aligned(16))) ushort As[4][128][8];
    __shared__ __attribute__((aligned(16))) ushort Bs[4][64][8];

    const int b  = blockIdx.x;
    const int bj = (b % 8) * 240 + b / 8;         // bijective (1920 % 8 == 0)
    const int m0 = (bj / 5) * 128, n0 = (bj % 5) * 64;

    f32x4 acc[4][2] = {};
    gemm128_core<10>(Xall, WfP, m0, n0, As, Bs, acc);

    const int t = threadIdx.x, l = t & 63, w = t >> 6;
    const int m_off = (w >> 1) * 64, n_off = (w & 1) * 32;
    const int col = l & 15, r0 = (l >> 4) * 4;
    #pragma unroll
    for (int mi = 0; mi < 4; ++mi) {
        #pragma unroll
        for (int ni = 0; ni < 2; ++ni) {
            const int gn = n0 + n_off + ni * 16 + col;
            const float bb = Bwf[gn];
            #pragma unroll
            for (int r = 0; r < 4; ++r) {
                const int gm = m0 + m_off + mi * 16 + r0 + r;
                WXFall[(size_t)gm * KP + gn] = f2bf(acc[mi][ni][r] + bb);
            }
        }
    }
}

__device__ __forceinline__ int swz640(int b) { return (b % 8) * 80 + b / 8; }

// ---------------------------------------------------------------------------
// FP = Hbf @ u_f^T + b_uf  (bf16 out, [4096][320]).  Grid 640 x 128 thr.
// Register-direct: lane (kq,lr) loads its own 16B fragments; no LDS/barriers.
// ---------------------------------------------------------------------------
__global__ __launch_bounds__(128)
void fp_kernel(const ushort* __restrict__ Hbf, const ushort* __restrict__ Uf,
               const float* __restrict__ BUF, ushort* __restrict__ FP)
{
    const int bj = swz640((int)blockIdx.x);
    const int m0 = (bj / 10) * 64, n0 = (bj % 10) * 32;
    const int t = threadIdx.x, w = t >> 6, l = t & 63;
    const int kq = l >> 4, lr = l & 15, m_off = w * 32;

    f32x4 acc[2][2] = {};
    #pragma unroll
    for (int s = 0; s < 10; ++s) {
        const int kc = s * 4 + kq;
        bf16x8 af[2], bfr[2];
        #pragma unroll
        for (int mi = 0; mi < 2; ++mi)
            af[mi] = *reinterpret_cast<const bf16x8*>(
                Hbf + (size_t)(m0 + m_off + mi * 16 + lr) * KP + (size_t)kc * 8);
        #pragma unroll
        for (int ni = 0; ni < 2; ++ni)
            bfr[ni] = *reinterpret_cast<const bf16x8*>(
                Uf + (size_t)(n0 + ni * 16 + lr) * KP + (size_t)kc * 8);
        #pragma unroll
        for (int mi = 0; mi < 2; ++mi)
            #pragma unroll
            for (int ni = 0; ni < 2; ++ni)
                acc[mi][ni] = __builtin_amdgcn_mfma_f32_16x16x32_bf16(
                    af[mi], bfr[ni], acc[mi][ni], 0, 0, 0);
    }

    const int col = l & 15, r0 = (l >> 4) * 4;
    #pragma unroll
    for (int mi = 0; mi < 2; ++mi) {
        #pragma unroll
        for (int ni = 0; ni < 2; ++ni) {
            const int gn = n0 + ni * 16 + col;
            const float bb = BUF[gn];
            #pragma unroll
            for (int r = 0; r < 4; ++r) {
                const int gm = m0 + m_off + mi * 16 + r0 + r;
                FP[(size_t)gm * KP + gn] = f2bf(acc[mi][ni][r] + bb);
            }
        }
    }
}

// ---------------------------------------------------------------------------
// Child gather + masked sums.  4 nodes/block, vectorized.
// Loads are UNCONDITIONAL and prefetched (MLP); math stays masked.  Indices
// are always valid; level-0 garbage data is masked out (mask==0 everywhere).
// ---------------------------------------------------------------------------
__global__ __launch_bounds__(320)
void reduce_kernel(const ushort* __restrict__ Hbf, const float* __restrict__ Cst,
                   const ushort* __restrict__ FP, const ushort* __restrict__ WXF,
                   const int* __restrict__ cidx, const float* __restrict__ cmask,
                   ushort* __restrict__ HT, float* __restrict__ SC)
{
    const int x = threadIdx.x;          // 0..79
    const int ty = threadIdx.y;         // 0..3
    const int n = blockIdx.x * 4 + ty;
    __shared__ int   ch[4][KK];
    __shared__ float mk[4][KK];
    if (x < KK) {
        ch[ty][x] = cidx[n * KK + x];
        mk[ty][x] = cmask[n * KK + x];
    }
    __syncthreads();
    if (x >= 75) return;
    const int h = x * 4;

    // prefetch all child rows (branchless -> max loads in flight)
    ushort4 hu[KK]; ushort4 fu[KK]; float4 cv[KK];
    #pragma unroll
    for (int k = 0; k < KK; ++k) {
        const size_t cr = (size_t)ch[ty][k];
        hu[k] = *reinterpret_cast<const ushort4*>(&Hbf[cr * KP + h]);
        fu[k] = *reinterpret_cast<const ushort4*>(&FP [cr * KP + h]);
        cv[k] = *reinterpret_cast<const float4*>(&Cst[cr * HH + h]);
    }

    ushort4 wxu = *reinterpret_cast<const ushort4*>(&WXF[(size_t)n * KP + h]);
    const float wx0 = bf2f(wxu.x), wx1 = bf2f(wxu.y),
                wx2 = bf2f(wxu.z), wx3 = bf2f(wxu.w);
    float ht0 = 0.f, ht1 = 0.f, ht2 = 0.f, ht3 = 0.f;
    float sc0 = 0.f, sc1 = 0.f, sc2 = 0.f, sc3 = 0.f;

    #pragma unroll
    for (int k = 0; k < KK; ++k) {
        const float m = mk[ty][k];
        if (m != 0.f) {                 // wave-mostly-uniform (per-node mask)
            ht0 += m * bf2f(hu[k].x); ht1 += m * bf2f(hu[k].y);
            ht2 += m * bf2f(hu[k].z); ht3 += m * bf2f(hu[k].w);
            sc0 += m * sigmoidf_(wx0 + bf2f(fu[k].x)) * cv[k].x;
            sc1 += m * sigmoidf_(wx1 + bf2f(fu[k].y)) * cv[k].y;
            sc2 += m * sigmoidf_(wx2 + bf2f(fu[k].z)) * cv[k].z;
            sc3 += m * sigmoidf_(wx3 + bf2f(fu[k].w)) * cv[k].w;
        }
    }
    ushort4 ho; ho.x = f2bf(ht0); ho.y = f2bf(ht1); ho.z = f2bf(ht2); ho.w = f2bf(ht3);
    *reinterpret_cast<ushort4*>(&HT[(size_t)n * KP + h]) = ho;
    float4 so; so.x = sc0; so.y = sc1; so.z = sc2; so.w = sc3;
    *reinterpret_cast<float4*>(&SC[(size_t)n * KP + h]) = so;
}

// ---------------------------------------------------------------------------
// zgemm: gates GEMM via global_load_lds staging + fused cell epilogue.
// Tile: 64 rows x 32 j-cols x 3 gates.  Grid 640 (64 m-tiles x 10 j-tiles),
// 256 thr (4 waves 2x2: wave = 32 rows x 16 j-cols).  K=640 concat [X|HT]:
// steps s<10 read X, s>=10 read HT (wave-uniform split).  LDS 10 KB,
// acc 24 VGPR/thread -> all 640 blocks co-resident; staging is DMA (no VGPR
// round-trip) -> deep load pipelining, unlike the old register-direct zcell.
// ---------------------------------------------------------------------------
__global__ __launch_bounds__(256)
void zgemm(const ushort* __restrict__ X, const ushort* __restrict__ HT,
           const ushort* __restrict__ Wz, const float* __restrict__ BZ,
           const float* __restrict__ SC,
           float* __restrict__ cdst, ushort* __restrict__ Hb,
           float* __restrict__ hdst)
{
    __shared__ __attribute__((aligned(16))) ushort As[4][64][8];     // 4 KB
    __shared__ __attribute__((aligned(16))) ushort Bs[3][4][32][8];  // 6 KB

    const int b  = blockIdx.x;
    const int bj = (b % 8) * 80 + b / 8;          // bijective (640 % 8 == 0)
    const int m0 = (bj / 10) * 64, j0 = (bj % 10) * 32;

    const int t = threadIdx.x, w = t >> 6, l = t & 63;
    const int kq = l >> 4, lr = l & 15;
    const int m_off = (w >> 1) * 32, j_off = (w & 1) * 16;

    // staging assignments
    const int arow = t & 63, akb = t >> 6;                 // A: 256 slots
    const int b0row = t & 31, b0kb = (t >> 5) & 3, b0g = t >> 7;       // B c=0
    const int i1 = t + 256;                                            // B c=1
    const int b1row = i1 & 31, b1kb = (i1 >> 5) & 3, b1g = i1 >> 7;

    f32x4 acc[3][2] = {};

    for (int s = 0; s < 20; ++s) {
        {   // ---- A stage (one 16B DMA per thread) ----
            const int kc = s * 4 + akb;
            const ushort* src = (s < 10)
                ? (X  + (size_t)(m0 + arow) * KP + (size_t)kc * 8)
                : (HT + (size_t)(m0 + arow) * KP + (size_t)(kc - 40) * 8);
            __builtin_amdgcn_global_load_lds((const GAS void*)src,
                (LAS void*)&As[akb][arow][0], 16, 0, 0);
        }
        {   // ---- B stage c=0 (256 of 384 slots) ----
            const int kc = s * 4 + b0kb;
            const ushort* src =
                Wz + ((size_t)b0g * KP + j0 + b0row) * 640 + (size_t)kc * 8;
            __builtin_amdgcn_global_load_lds((const GAS void*)src,
                (LAS void*)&Bs[b0g][b0kb][b0row][0], 16, 0, 0);
        }
        if (i1 < 384) {   // ---- B stage c=1 (wave-uniform predicate) ----
            const int kc = s * 4 + b1kb;
            const ushort* src =
                Wz + ((size_t)b1g * KP + j0 + b1row) * 640 + (size_t)kc * 8;
            __builtin_amdgcn_global_load_lds((const GAS void*)src,
                (LAS void*)&Bs[b1g][b1kb][b1row][0], 16, 0, 0);
        }
        __syncthreads();

        bf16x8 af[2], bfr[3];
        #pragma unroll
        for (int mi = 0; mi < 2; ++mi)
            af[mi] = *reinterpret_cast<const bf16x8*>(
                &As[kq][m_off + mi * 16 + lr][0]);
        #pragma unroll
        for (int g = 0; g < 3; ++g)
            bfr[g] = *reinterpret_cast<const bf16x8*>(
                &Bs[g][kq][j_off + lr][0]);
        #pragma unroll
        for (int g = 0; g < 3; ++g)
            #pragma unroll
            for (int mi = 0; mi < 2; ++mi)
                acc[g][mi] = __builtin_amdgcn_mfma_f32_16x16x32_bf16(
                    af[mi], bfr[g], acc[g][mi], 0, 0, 0);
        __syncthreads();
    }

    // ---- fused cell epilogue (all 3 gates present per element) ----------
    const int col = l & 15, r0 = (l >> 4) * 4;
    const int gn = j0 + j_off + col;
    if (gn < 300) {
        const float bi_ = BZ[gn], bo_ = BZ[KP + gn], bu_ = BZ[2 * KP + gn];
        #pragma unroll
        for (int mi = 0; mi < 2; ++mi) {
            #pragma unroll
            for (int r = 0; r < 4; ++r) {
                const int gm = m0 + m_off + mi * 16 + r0 + r;
                const float sc = SC[(size_t)gm * KP + gn];
                const float ig = sigmoidf_(acc[0][mi][r] + bi_);
                const float og = sigmoidf_(acc[1][mi][r] + bo_);
                const float ug = tanhf   (acc[2][mi][r] + bu_);
                const float c  = ig * ug + sc;
                const float hv = og * tanhf(c);
                cdst[(size_t)gm * HH + gn] = c;
                Hb  [(size_t)gm * KP + gn] = f2bf(hv);
                if (hdst) hdst[(size_t)gm * HH + gn] = hv;
            }
        }
    }
}

// ---------------------------------------------------------------------------
extern "C" void kernel_launch(void* const* d_in, const int* in_sizes, int n_in,
                              void* d_out, int out_size, void* d_ws, size_t ws_size,
                              hipStream_t stream)
{
    const int*   word_ids   = (const int*)  d_in[0];
    const int*   child_idx  = (const int*)  d_in[1];
    const float* child_mask = (const float*)d_in[2];
    const float* emb        = (const float*)d_in[3];
    const float* w_i  = (const float*)d_in[4];  const float* b_wi = (const float*)d_in[5];
    const float* u_i  = (const float*)d_in[6];  const float* b_ui = (const float*)d_in[7];
    const float* w_f  = (const float*)d_in[8];  const float* b_wf = (const float*)d_in[9];
    const float* u_f  = (const float*)d_in[10]; const float* b_uf = (const float*)d_in[11];
    const float* w_o  = (const float*)d_in[12]; const float* b_wo = (const float*)d_in[13];
    const float* u_o  = (const float*)d_in[14]; const float* b_uo = (const float*)d_in[15];
    const float* w_u  = (const float*)d_in[16]; const float* b_wu = (const float*)d_in[17];
    const float* u_u  = (const float*)d_in[18]; const float* b_uu = (const float*)d_in[19];

    uint8_t* ws = (uint8_t*)d_ws;
    size_t off = 0;
    auto alloc = [&](size_t bytes) {
        uint8_t* p = ws + off;
        off += (bytes + 255) & ~(size_t)255;
        return p;
    };
    ushort* WfP   = (ushort*)alloc((size_t)KP * KP * 2);
    ushort* Uf    = (ushort*)alloc((size_t)KP * KP * 2);
    ushort* Wz    = (ushort*)alloc((size_t)3 * KP * 640 * 2);
    ushort* Xall  = (ushort*)alloc((size_t)LVLS * NN * KP * 2);
    ushort* WXFall= (ushort*)alloc((size_t)LVLS * NN * KP * 2);
    ushort* FPbf  = (ushort*)alloc((size_t)NN * KP * 2);
    ushort* HTbf  = (ushort*)alloc((size_t)NN * KP * 2);
    ushort* Hbf   = (ushort*)alloc((size_t)NN * KP * 2);
    float*  SCb   = (float*) alloc((size_t)NN * KP * 4);
    float*  C0    = (float*) alloc((size_t)NN * HH * 4);
    float*  BZ    = (float*) alloc(3 * KP * 4);
    float*  Bwf   = (float*) alloc(KP * 4);
    float*  BUFb  = (float*) alloc(KP * 4);

    pack_and_stage<<<18567, 256, 0, stream>>>(
        w_i, b_wi, u_i, b_ui, w_f, b_wf, u_f, b_uf,
        w_o, b_wo, u_o, b_uo, w_u, b_wu, u_u, b_uu,
        WfP, Uf, Wz, BZ, Bwf, BUFb,
        word_ids, emb, Xall);
    wxf_all_kernel<<<1920, 256, 0, stream>>>(Xall, WfP, Bwf, WXFall);

    float* h_final = (float*)d_out;
    float* c_final = (float*)d_out + (size_t)NN * HH;

    for (int lev = 0; lev < LVLS; ++lev) {
        const int*    cidx  = child_idx  + (size_t)lev * NN * KK;
        const float*  cmask = child_mask + (size_t)lev * NN * KK;
        const ushort* Xlev  = Xall   + (size_t)lev * NN * KP;
        const ushort* WXFlev= WXFall + (size_t)lev * NN * KP;
        const bool last = (lev == LVLS - 1);
        float* cdst = last ? c_final : C0;
        float* hdst = last ? h_final : nullptr;

        if (lev > 0)
            fp_kernel<<<640, 128, 0, stream>>>(Hbf, Uf, BUFb, FPbf);
        reduce_kernel<<<1024, dim3(80, 4), 0, stream>>>(
            Hbf, C0, FPbf, WXFlev, cidx, cmask, HTbf, SCb);
        zgemm<<<640, 256, 0, stream>>>(
            Xlev, HTbf, Wz, BZ, SCb, cdst, Hbf, hdst);
    }
}